// Round 3
// baseline (334.491 us; speedup 1.0000x reference)
//
#include <hip/hip_runtime.h>

// RNN: h_t = tanh(x_t * W_ih^T + b_ih + h W_hh^T + b_hh), out = h_T W_fc^T + b_fc
// B=8192, T=784, I=1, H=30 (pad 32), C=10. fp32.
//
// R3: TPB=32, ROWS=1. Each lane owns ONE row of W_hh (32 floats incl. pad)
// so total live regs ~52 fits the compiler's 8-wave (<=64 VGPR) budget ->
// weights stay resident (R1/R2 with 128/64-float slices were rematerialized
// from L1 every step: VGPR_Count came back 84/48). 8192 batches x 32 thr
// = 4096 waves = 4/SIMD -> DS latency hidden. A batch's 32 threads are
// wave-local (2 batches/wave) -> no __syncthreads, just wave_barrier ordering.

#define TT 784
#define HH 30
#define HP 32
#define CC 10
#define TPB 32
#define NB 8       // batches per 256-thread block
#define LSTR 36    // LDS row stride in floats (144 B, 16B-aligned for b128)

__global__ __launch_bounds__(256, 4)
void rnn_scan_kernel(const float* __restrict__ x,
                     const float* __restrict__ W_ih,
                     const float* __restrict__ W_hh,
                     const float* __restrict__ b_ih,
                     const float* __restrict__ b_hh,
                     const float* __restrict__ W_fc,
                     const float* __restrict__ b_fc,
                     float* __restrict__ out) {
    __shared__ float hbuf[NB * LSTR];

    const int tid = threadIdx.x;
    const int bl  = tid >> 5;          // local batch 0..7 (2 per wave)
    const int r   = tid & 31;          // owned row of W_hh (30,31 = pad)
    const int b   = blockIdx.x * NB + bl;

    // --- per-lane weights: one row of W_hh (32 floats, zero-padded) ---
    float w[HP];
    const bool valid = (r < HH);
#pragma unroll
    for (int j = 0; j < HP; ++j)
        w[j] = (valid && (j < HH)) ? W_hh[r * HH + j] : 0.0f;
    const float bias = valid ? (b_ih[r] + b_hh[r]) : 0.0f;
    const float wih  = valid ? W_ih[r] : 0.0f;

    float* hp = &hbuf[bl * LSTR];
    hp[r] = 0.0f;                       // h0 = 0 (also zeroes pad rows)
    __builtin_amdgcn_wave_barrier();

    const float* xb = x + (size_t)b * TT;
    float4 xq = *(const float4*)(xb);

    for (int q = 0; q < TT / 4; ++q) {
        float4 nxt = (q + 1 < TT / 4) ? *(const float4*)(xb + (q + 1) * 4)
                                      : make_float4(0.f, 0.f, 0.f, 0.f);
#pragma unroll
        for (int u = 0; u < 4; ++u) {
            const float xt = (u == 0) ? xq.x : (u == 1) ? xq.y
                           : (u == 2) ? xq.z : xq.w;
            // two independent FMA chains over the 32-wide dot product
            float a0 = __builtin_fmaf(xt, wih, bias);
            float a1 = 0.0f;
#pragma unroll
            for (int jq = 0; jq < HP / 4; ++jq) {
                const float4 hq = *(const float4*)(hp + jq * 4);
                a0 = __builtin_fmaf(w[jq * 4 + 0], hq.x, a0);
                a1 = __builtin_fmaf(w[jq * 4 + 1], hq.y, a1);
                a0 = __builtin_fmaf(w[jq * 4 + 2], hq.z, a0);
                a1 = __builtin_fmaf(w[jq * 4 + 3], hq.w, a1);
            }
            const float acc = a0 + a1;
            // tanh(a) = 1 - 2/(e^{2a}+1);  e^{2a} = 2^{a * 2*log2(e)}
            const float e  = __builtin_exp2f(acc * 2.885390081777927f);
            const float hn = __builtin_fmaf(-2.0f,
                                 __builtin_amdgcn_rcpf(e + 1.0f), 1.0f);
            __builtin_amdgcn_wave_barrier();   // reads(t) before write(t)
            hp[r] = hn;                        // pad rows: tanh(0)=0 -> stays 0
            __builtin_amdgcn_wave_barrier();   // write(t) before reads(t+1)
        }
        xq = nxt;
    }

    // --- FC head: lanes r<10 each produce one output ---
    if (r < CC) {
        float acc = b_fc[r];
#pragma unroll
        for (int j = 0; j < HH; ++j)
            acc = __builtin_fmaf(W_fc[r * HH + j], hp[j], acc);
        out[(size_t)b * CC + r] = acc;
    }
}

extern "C" void kernel_launch(void* const* d_in, const int* in_sizes, int n_in,
                              void* d_out, int out_size, void* d_ws, size_t ws_size,
                              hipStream_t stream) {
    const float* x    = (const float*)d_in[0];
    const float* W_ih = (const float*)d_in[1];
    const float* W_hh = (const float*)d_in[2];
    const float* b_ih = (const float*)d_in[3];
    const float* b_hh = (const float*)d_in[4];
    const float* W_fc = (const float*)d_in[5];
    const float* b_fc = (const float*)d_in[6];

    hipLaunchKernelGGL(rnn_scan_kernel,
                       dim3(8192 / NB), dim3(NB * TPB), 0, stream,
                       x, W_ih, W_hh, b_ih, b_hh, W_fc, b_fc,
                       (float*)d_out);
}

// Round 4
// 323.550 us; speedup vs baseline: 1.0338x; 1.0338x over previous
//
#include <hip/hip_runtime.h>

// RNN: h_t = tanh(x_t * W_ih^T + b_ih + h W_hh^T + b_hh), out = h_T W_fc^T + b_fc
// B=8192, T=784, I=1, H=30 (pad 32), C=10. fp32.
//
// R4 = R3 + inline-asm register pinning of the per-lane W_hh row.
// R1/R2/R3 all came back with VGPR_Count too small to hold the weight slice
// (84/48/36): the allocator rematerializes the weight loads inside the step
// loop (~3x VALU instruction bloat, VALUBusy 94% at 300us). The empty asm
// with "+v" operands claims to modify the 32 weight values, making remat
// illegal -> weights become opaque, resident VGPRs.
//
// Layout: TPB=32 (lane r owns row r of W_hh), 2 batches per wave, h[32] per
// batch in LDS exchanged wave-locally (no __syncthreads; wave_barrier only).
// 1024 blocks x 256 thr = 4096 waves = 4/SIMD.

#define TT 784
#define HH 30
#define HP 32
#define CC 10
#define TPB 32
#define NB 8       // batches per 256-thread block
#define LSTR 36    // LDS row stride in floats (144 B, 16B-aligned for b128)

__global__ __launch_bounds__(256, 4)
void rnn_scan_kernel(const float* __restrict__ x,
                     const float* __restrict__ W_ih,
                     const float* __restrict__ W_hh,
                     const float* __restrict__ b_ih,
                     const float* __restrict__ b_hh,
                     const float* __restrict__ W_fc,
                     const float* __restrict__ b_fc,
                     float* __restrict__ out) {
    __shared__ float hbuf[NB * LSTR];

    const int tid = threadIdx.x;
    const int bl  = tid >> 5;          // local batch 0..7 (2 per wave)
    const int r   = tid & 31;          // owned row of W_hh (30,31 = pad)
    const int b   = blockIdx.x * NB + bl;

    // --- per-lane weights: one row of W_hh (32 floats, zero-padded) ---
    float w[HP];
    const bool valid = (r < HH);
#pragma unroll
    for (int j = 0; j < HP; ++j)
        w[j] = (valid && (j < HH)) ? W_hh[r * HH + j] : 0.0f;
    float bias = valid ? (b_ih[r] + b_hh[r]) : 0.0f;
    float wih  = valid ? W_ih[r] : 0.0f;

    // Pin the weights into VGPRs: the asm "modifies" them, so the compiler
    // cannot re-materialize the global loads inside the step loop.
    asm volatile("" : "+v"(w[0]),  "+v"(w[1]),  "+v"(w[2]),  "+v"(w[3]),
                      "+v"(w[4]),  "+v"(w[5]),  "+v"(w[6]),  "+v"(w[7]),
                      "+v"(w[8]),  "+v"(w[9]),  "+v"(w[10]), "+v"(w[11]),
                      "+v"(w[12]), "+v"(w[13]), "+v"(w[14]), "+v"(w[15]));
    asm volatile("" : "+v"(w[16]), "+v"(w[17]), "+v"(w[18]), "+v"(w[19]),
                      "+v"(w[20]), "+v"(w[21]), "+v"(w[22]), "+v"(w[23]),
                      "+v"(w[24]), "+v"(w[25]), "+v"(w[26]), "+v"(w[27]),
                      "+v"(w[28]), "+v"(w[29]), "+v"(w[30]), "+v"(w[31]));
    asm volatile("" : "+v"(bias), "+v"(wih));

    float* hp = &hbuf[bl * LSTR];
    hp[r] = 0.0f;                       // h0 = 0 (also zeroes pad rows)
    __builtin_amdgcn_wave_barrier();

    const float* xb = x + (size_t)b * TT;
    float4 xq = *(const float4*)(xb);

    for (int q = 0; q < TT / 4; ++q) {
        float4 nxt = (q + 1 < TT / 4) ? *(const float4*)(xb + (q + 1) * 4)
                                      : make_float4(0.f, 0.f, 0.f, 0.f);
#pragma unroll
        for (int u = 0; u < 4; ++u) {
            const float xt = (u == 0) ? xq.x : (u == 1) ? xq.y
                           : (u == 2) ? xq.z : xq.w;
            // two independent FMA chains over the 32-wide dot product
            float a0 = __builtin_fmaf(xt, wih, bias);
            float a1 = 0.0f;
#pragma unroll
            for (int jq = 0; jq < HP / 4; ++jq) {
                const float4 hq = *(const float4*)(hp + jq * 4);
                a0 = __builtin_fmaf(w[jq * 4 + 0], hq.x, a0);
                a1 = __builtin_fmaf(w[jq * 4 + 1], hq.y, a1);
                a0 = __builtin_fmaf(w[jq * 4 + 2], hq.z, a0);
                a1 = __builtin_fmaf(w[jq * 4 + 3], hq.w, a1);
            }
            const float acc = a0 + a1;
            // tanh(a) = 1 - 2/(e^{2a}+1);  e^{2a} = 2^{a * 2*log2(e)}
            const float e  = __builtin_exp2f(acc * 2.885390081777927f);
            const float hn = __builtin_fmaf(-2.0f,
                                 __builtin_amdgcn_rcpf(e + 1.0f), 1.0f);
            __builtin_amdgcn_wave_barrier();   // reads(t) before write(t)
            hp[r] = hn;                        // pad rows: tanh(0)=0 -> stays 0
            __builtin_amdgcn_wave_barrier();   // write(t) before reads(t+1)
        }
        xq = nxt;
    }

    // --- FC head: lanes r<10 each produce one output ---
    if (r < CC) {
        float acc = b_fc[r];
#pragma unroll
        for (int j = 0; j < HH; ++j)
            acc = __builtin_fmaf(W_fc[r * HH + j], hp[j], acc);
        out[(size_t)b * CC + r] = acc;
    }
}

extern "C" void kernel_launch(void* const* d_in, const int* in_sizes, int n_in,
                              void* d_out, int out_size, void* d_ws, size_t ws_size,
                              hipStream_t stream) {
    const float* x    = (const float*)d_in[0];
    const float* W_ih = (const float*)d_in[1];
    const float* W_hh = (const float*)d_in[2];
    const float* b_ih = (const float*)d_in[3];
    const float* b_hh = (const float*)d_in[4];
    const float* W_fc = (const float*)d_in[5];
    const float* b_fc = (const float*)d_in[6];

    hipLaunchKernelGGL(rnn_scan_kernel,
                       dim3(8192 / NB), dim3(NB * TPB), 0, stream,
                       x, W_ih, W_hh, b_ih, b_hh, W_fc, b_fc,
                       (float*)d_out);
}